// Round 12
// baseline (45.439 us; speedup 1.0000x reference)
//
#include <hip/hip_runtime.h>

// SmileResampler: out[b,bh,h,w] = lerp over band axis of x at
// iy = clip(bh + clip(ws[b,bh,w],-2,2), 0, 127) * (128/127) - 0.5
// Shapes: x (4,128,256,256) f32, ws (4,128,256) f32, out same as x.
//
// R12: wave-private staging, ZERO barriers. Each wave owns
// (b, h, wg: 64-w group, bg: 16-band group) and stages its own 22 halo
// rows x 64 w (5.5 KiB) into a wave-private LDS slice via global_load_lds
// (size=4 -> 256 B per inst, contiguous dest). No cross-wave LDS deps ->
// no s_barrier; the only wait is the wave's own vmcnt(0) after issuing
// all 22 stage + 16 ws loads. Waves retire independently -> smooth HBM
// demand (vs barrier-phase-locked blocks of R5-R11).
// Block = 4 waves = 4 adjacent band-groups at fixed (b,h,wg): halo rows
// overlap pairwise -> L1/L2 hits. LDS 22 KiB/block -> 7 blocks/CU = 28
// waves (87%). XCD-chunked swizzle keeps a (b,h)'s blocks on one XCD.
// LDS reads: addr = r*64 + lane -> bank = lane%32 -> 2-way alias (free).

#define BH_ 128
#define H_  256
#define W_  256
#define BG   16          // output bands per wave
#define NR   22          // staged rows per wave (BG + 3-halo each side)

__global__ __launch_bounds__(256, 7) void smile_kernel(
    const float* __restrict__ x,
    const float* __restrict__ ws,
    float* __restrict__ out)
{
    __shared__ float tile[4][NR * 64];   // per-wave private slices, 22 KiB

    const int t    = threadIdx.x;
    const int wv   = t >> 6;             // 0..3
    const int lane = t & 63;

    // XCD-chunked bijective swizzle (nwg = 8192, 8 XCDs, chunk = 1024)
    const int bid0 = blockIdx.x;
    const int bid  = (bid0 & 7) * 1024 + (bid0 >> 3);

    // bid -> (b, h, wg, bgb): consecutive bids = adjacent band-halves
    const int bgb = bid & 1;             // band-group half: 0 -> bg 0..3, 1 -> 4..7
    int rem = bid >> 1;
    const int wg  = rem & 3;             // 64-w group
    rem >>= 2;
    const int h   = rem & (H_ - 1);
    const int b   = rem >> 8;

    const int bg  = bgb * 4 + wv;        // this wave's band group (0..7)
    const int bh0 = bg * BG;             // first output band
    const int w   = wg * 64 + lane;

    float* const tl = &tile[wv][0];

    // ---- stage 22 halo rows (wave-private, async, no VGPR round-trip) ----
#pragma unroll
    for (int i = 0; i < NR; ++i) {
        const int band = min(max(bh0 - 3 + i, 0), BH_ - 1);
        const float* gp = x + ((size_t)(b * BH_ + band) * H_ + h) * W_ + w;
        __builtin_amdgcn_global_load_lds(
            (const __attribute__((address_space(1))) void*)gp,
            (__attribute__((address_space(3))) void*)&tl[i * 64],
            4, 0, 0);
    }

    // ---- 16 ws loads (issued while staging is in flight) ----
    const float* __restrict__ wsp = ws + (size_t)(b * BH_ + bh0) * W_ + w;
    float s[BG];
#pragma unroll
    for (int r = 0; r < BG; ++r)
        s[r] = wsp[r * W_];

    // own-wave drain; no barrier (LDS slice is wave-private)
    asm volatile("s_waitcnt vmcnt(0)" ::: "memory");

    // ---- compute + store 16 bands ----
    const float scale = (float)(128.0 / 127.0);
    float* __restrict__ outp =
        out + ((size_t)(b * BH_ + bh0) * H_ + h) * W_ + w;

#pragma unroll
    for (int r = 0; r < BG; ++r) {
        const int bh  = bh0 + r;
        float sc      = fminf(fmaxf(s[r], -2.0f), 2.0f);
        float shifted = fminf(fmaxf((float)bh + sc, 0.0f), (float)(BH_ - 1));
        float iy      = fmaf(shifted, scale, -0.5f);
        float i0f     = floorf(iy);
        float frac    = iy - i0f;
        int   i0      = (int)i0f;
        int   r0      = min(max(i0, 0), BH_ - 1) - (bh0 - 3);
        int   r1      = min(i0 + 1, BH_ - 1) - (bh0 - 3);
        float x0 = tl[r0 * 64 + lane];
        float x1 = tl[r1 * 64 + lane];
        __builtin_nontemporal_store(fmaf(frac, x1 - x0, x0),
                                    outp + (size_t)r * (H_ * W_));
    }
}

extern "C" void kernel_launch(void* const* d_in, const int* in_sizes, int n_in,
                              void* d_out, int out_size, void* d_ws, size_t ws_size,
                              hipStream_t stream) {
    const float* x  = (const float*)d_in[0];
    const float* ws = (const float*)d_in[1];
    float* out = (float*)d_out;

    // waves = 4 batches * 256 h * 4 wgroups * 8 bgroups = 32768 -> 8192 blocks
    const int grid = 8192;
    smile_kernel<<<grid, 256, 0, stream>>>(x, ws, out);
}